// Round 1
// baseline (6988.580 us; speedup 1.0000x reference)
//
#include <hip/hip_runtime.h>
#include <math.h>

#define Lnum 8
#define Bn 4
#define Tn 2048
#define Dn 256
#define Sn 512
#define BT (Bn*Tn)   // 8192

// ---------------- phase-preserving RMS norm: h[BT,D,2] -> xr[BT,D], xi[BT,D]
__global__ __launch_bounds__(256)
void norm_kernel(const float* __restrict__ h, const float* __restrict__ g,
                 float* __restrict__ xr, float* __restrict__ xi)
{
    const int bt = blockIdx.x;
    const int d  = threadIdx.x;          // D = 256 threads
    const float2 v = reinterpret_cast<const float2*>(h)[(size_t)bt*Dn + d];
    float sum = v.x*v.x + v.y*v.y;
    #pragma unroll
    for (int o = 32; o > 0; o >>= 1) sum += __shfl_down(sum, o);
    __shared__ float ws4[4];
    if ((threadIdx.x & 63) == 0) ws4[threadIdx.x >> 6] = sum;
    __syncthreads();
    const float tot = ws4[0] + ws4[1] + ws4[2] + ws4[3];
    const float rms = sqrtf(tot * (1.0f/Dn) + 1e-6f);
    const float scale = g[d] / rms;
    xr[(size_t)bt*Dn + d] = v.x * scale;
    xi[(size_t)bt*Dn + d] = v.y * scale;
}

// ---------------- final norm, writes interleaved output
__global__ __launch_bounds__(256)
void out_norm_kernel(const float* __restrict__ h, const float* __restrict__ g,
                     float* __restrict__ out)
{
    const int bt = blockIdx.x;
    const int d  = threadIdx.x;
    const float2 v = reinterpret_cast<const float2*>(h)[(size_t)bt*Dn + d];
    float sum = v.x*v.x + v.y*v.y;
    #pragma unroll
    for (int o = 32; o > 0; o >>= 1) sum += __shfl_down(sum, o);
    __shared__ float ws4[4];
    if ((threadIdx.x & 63) == 0) ws4[threadIdx.x >> 6] = sum;
    __syncthreads();
    const float tot = ws4[0] + ws4[1] + ws4[2] + ws4[3];
    const float rms = sqrtf(tot * (1.0f/Dn) + 1e-6f);
    const float scale = g[d] / rms;
    float2 o; o.x = v.x * scale; o.y = v.y * scale;
    reinterpret_cast<float2*>(out)[(size_t)bt*Dn + d] = o;
}

// ---------------- generic dual GEMM: C = [beta*C +] (A1@W1 + s2*A2@W2) [+bias][sigmoid]
// A row-major [M,K], W row-major [K,N], C row-major [M,N]. M%64==0, N%64==0, K%16==0.
#define GBM 64
#define GBN 64
#define GBK 16
__global__ __launch_bounds__(256)
void gemm_dual(const float* __restrict__ A1, const float* __restrict__ A2,
               const float* __restrict__ W1, const float* __restrict__ W2,
               const float s2, const float* __restrict__ bias, const int do_sig,
               const int accum, float* __restrict__ C,
               const int M, const int N, const int K)
{
    __shared__ float As1[GBM][GBK+1];
    __shared__ float As2[GBM][GBK+1];
    __shared__ float Bs1[GBK][GBN];
    __shared__ float Bs2[GBK][GBN];
    const int tid = threadIdx.x;
    const int tx = tid & 15, ty = tid >> 4;
    const int row0 = blockIdx.y * GBM, col0 = blockIdx.x * GBN;

    float acc1[4][4] = {{0.f}}, acc2[4][4] = {{0.f}};

    for (int k0 = 0; k0 < K; k0 += GBK) {
        #pragma unroll
        for (int i = tid; i < GBM*GBK; i += 256) {
            const int r = i >> 4, c = i & 15;
            As1[r][c] = A1[(size_t)(row0 + r)*K + k0 + c];
            As2[r][c] = A2[(size_t)(row0 + r)*K + k0 + c];
        }
        #pragma unroll
        for (int i = tid; i < GBK*GBN; i += 256) {
            const int r = i >> 6, c = i & 63;
            Bs1[r][c] = W1[(size_t)(k0 + r)*N + col0 + c];
            Bs2[r][c] = W2[(size_t)(k0 + r)*N + col0 + c];
        }
        __syncthreads();
        #pragma unroll
        for (int kk = 0; kk < GBK; ++kk) {
            float a1[4], a2[4], b1[4], b2[4];
            #pragma unroll
            for (int i = 0; i < 4; ++i) { a1[i] = As1[ty*4+i][kk]; a2[i] = As2[ty*4+i][kk]; }
            #pragma unroll
            for (int j = 0; j < 4; ++j) { b1[j] = Bs1[kk][tx*4+j]; b2[j] = Bs2[kk][tx*4+j]; }
            #pragma unroll
            for (int i = 0; i < 4; ++i)
                #pragma unroll
                for (int j = 0; j < 4; ++j) {
                    acc1[i][j] = fmaf(a1[i], b1[j], acc1[i][j]);
                    acc2[i][j] = fmaf(a2[i], b2[j], acc2[i][j]);
                }
        }
        __syncthreads();
    }

    #pragma unroll
    for (int i = 0; i < 4; ++i) {
        const int row = row0 + ty*4 + i;
        #pragma unroll
        for (int j = 0; j < 4; ++j) {
            const int col = col0 + tx*4 + j;
            float v = acc1[i][j] + s2 * acc2[i][j];
            if (bias) v += bias[col];
            if (do_sig) v = 1.0f / (1.0f + expf(-v));
            const size_t idx = (size_t)row*N + col;
            if (accum) v += C[idx];
            C[idx] = v;
        }
    }
}

// ---------------- sequential scan over T, one thread per (b,s) channel.
// In-place: bxr/bxi are overwritten with hs_r/hs_i (read-before-write per step).
__global__ __launch_bounds__(256)
void scan_kernel(float* __restrict__ bxr, float* __restrict__ bxi,
                 const float* __restrict__ gate,
                 const float* __restrict__ theta, const float* __restrict__ dp,
                 const float* __restrict__ h0)
{
    const int idx = blockIdx.x * blockDim.x + threadIdx.x; // 0 .. B*S-1
    if (idx >= Bn*Sn) return;
    const int b = idx / Sn, s = idx % Sn;
    const float th = theta[s];
    const float ct = cosf(th), st = sinf(th);
    const float damp = 0.5f + 0.5f / (1.0f + expf(-dp[s]));
    float hr = h0[((size_t)b*Sn + s)*2 + 0];
    float hi = h0[((size_t)b*Sn + s)*2 + 1];
    for (int t = 0; t < Tn; ++t) {
        const size_t off = ((size_t)b*Tn + t)*Sn + s;
        const float br = bxr[off], bi = bxi[off], g = gate[off];
        const float rr = ct*hr - st*hi;
        const float ri = st*hr + ct*hi;
        const float om = (1.0f - g) * damp;
        hr = g*br + om*rr;
        hi = g*bi + om*ri;
        bxr[off] = hr;
        bxi[off] = hi;
    }
}

// ---------------- residual + nonlinearity: h += 0.1 * ((1+y_r)*y)
__global__ __launch_bounds__(256)
void resid_kernel(float* __restrict__ h, const float* __restrict__ yr,
                  const float* __restrict__ yi)
{
    const size_t idx = (size_t)blockIdx.x * blockDim.x + threadIdx.x;
    const float a = yr[idx], b = yi[idx];
    float2 v = reinterpret_cast<float2*>(h)[idx];
    v.x += 0.1f * (a*a + a);
    v.y += 0.1f * (a*b + b);
    reinterpret_cast<float2*>(h)[idx] = v;
}

extern "C" void kernel_launch(void* const* d_in, const int* in_sizes, int n_in,
                              void* d_out, int out_size, void* d_ws, size_t ws_size,
                              hipStream_t stream)
{
    const float* x      = (const float*)d_in[0];
    const float* h0     = (const float*)d_in[1];
    const float* theta  = (const float*)d_in[2];
    const float* dp     = (const float*)d_in[3];
    const float* B_wr   = (const float*)d_in[4];
    const float* B_wi   = (const float*)d_in[5];
    const float* C_wr   = (const float*)d_in[6];
    const float* C_wi   = (const float*)d_in[7];
    const float* D_wr   = (const float*)d_in[8];
    const float* D_wi   = (const float*)d_in[9];
    const float* gate_w = (const float*)d_in[10];
    const float* gate_b = (const float*)d_in[11];
    const float* norm_g = (const float*)d_in[12];
    const float* out_g  = (const float*)d_in[13];
    float* out = (float*)d_out;

    float* ws = (float*)d_ws;
    size_t off = 0;
    float* xr  = ws + off; off += (size_t)BT*Dn;
    float* xi  = ws + off; off += (size_t)BT*Dn;
    float* bxr = ws + off; off += (size_t)BT*Sn;   // becomes hs_r after scan
    float* bxi = ws + off; off += (size_t)BT*Sn;   // becomes hs_i after scan
    float* gt  = ws + off; off += (size_t)BT*Sn;
    float* yr  = ws + off; off += (size_t)BT*Dn;
    float* yi  = ws + off; off += (size_t)BT*Dn;
    float* h   = ws + off; off += (size_t)BT*Dn*2;

    hipMemcpyAsync(h, x, sizeof(float)*(size_t)BT*Dn*2, hipMemcpyDeviceToDevice, stream);

    const dim3 gS(Sn/GBN, BT/GBM);   // (8,128)  N=512 GEMMs
    const dim3 gD(Dn/GBN, BT/GBM);   // (4,128)  N=256 GEMMs

    for (int l = 0; l < Lnum; ++l) {
        const float* bwr = B_wr   + (size_t)l*Dn*Sn;
        const float* bwi = B_wi   + (size_t)l*Dn*Sn;
        const float* cwr = C_wr   + (size_t)l*Sn*Dn;
        const float* cwi = C_wi   + (size_t)l*Sn*Dn;
        const float* dwr = D_wr   + (size_t)l*Dn*Dn;
        const float* dwi = D_wi   + (size_t)l*Dn*Dn;
        const float* gw  = gate_w + (size_t)l*2*Dn*Sn;
        const float* gb  = gate_b + (size_t)l*Sn;

        norm_kernel<<<BT, 256, 0, stream>>>(h, norm_g + (size_t)l*Dn, xr, xi);

        // bx_r = xr@Bwr - xi@Bwi ; bx_i = xr@Bwi + xi@Bwr
        gemm_dual<<<gS, 256, 0, stream>>>(xr, xi, bwr, bwi, -1.0f, nullptr, 0, 0, bxr, BT, Sn, Dn);
        gemm_dual<<<gS, 256, 0, stream>>>(xr, xi, bwi, bwr, +1.0f, nullptr, 0, 0, bxi, BT, Sn, Dn);
        // gate = sigmoid([xr,xi]@gw + gb)
        gemm_dual<<<gS, 256, 0, stream>>>(xr, xi, gw, gw + (size_t)Dn*Sn, +1.0f, gb, 1, 0, gt, BT, Sn, Dn);
        // y = dx = x@Dw (complex)
        gemm_dual<<<gD, 256, 0, stream>>>(xr, xi, dwr, dwi, -1.0f, nullptr, 0, 0, yr, BT, Dn, Dn);
        gemm_dual<<<gD, 256, 0, stream>>>(xr, xi, dwi, dwr, +1.0f, nullptr, 0, 0, yi, BT, Dn, Dn);

        // recurrence (in-place: bxr/bxi -> hs_r/hs_i)
        scan_kernel<<<(Bn*Sn)/256, 256, 0, stream>>>(bxr, bxi, gt,
                                                     theta + (size_t)l*Sn, dp + (size_t)l*Sn,
                                                     h0 + (size_t)l*Bn*Sn*2);

        // y += ch = hs@Cw (complex)
        gemm_dual<<<gD, 256, 0, stream>>>(bxr, bxi, cwr, cwi, -1.0f, nullptr, 0, 1, yr, BT, Dn, Sn);
        gemm_dual<<<gD, 256, 0, stream>>>(bxr, bxi, cwi, cwr, +1.0f, nullptr, 0, 1, yi, BT, Dn, Sn);

        // h += 0.1 * ((1+y_r)*y)
        resid_kernel<<<(BT*Dn)/256, 256, 0, stream>>>(h, yr, yi);
    }

    out_norm_kernel<<<BT, 256, 0, stream>>>(h, out_g, out);
}

// Round 2
// 1129.672 us; speedup vs baseline: 6.1864x; 6.1864x over previous
//
#include <hip/hip_runtime.h>
#include <hip/hip_bf16.h>
#include <math.h>

#define Lnum 8
#define Bn 4
#define Tn 2048
#define Dn 256
#define Sn 512
#define BT (Bn*Tn)      // 8192
#define CHK 32          // scan chunks
#define TC (Tn/CHK)     // 64

typedef __attribute__((ext_vector_type(8))) short bf16x8;
typedef __attribute__((ext_vector_type(4))) float f32x4;

__device__ __forceinline__ ushort f2bf(float f) {
    union { float f; unsigned u; } v; v.f = f;
    unsigned r = v.u + 0x7fffu + ((v.u >> 16) & 1u);   // RNE
    return (ushort)(r >> 16);
}

// direct global->LDS async copy, 16B per lane (dest = wave-uniform base + lane*16)
__device__ __forceinline__ void gload16(const void* g, void* l) {
    using u32 = unsigned int;
    auto gp = (const __attribute__((address_space(1))) u32*)(uintptr_t)g;
    auto lp = (__attribute__((address_space(3))) u32*)(uintptr_t)l;
    __builtin_amdgcn_global_load_lds(gp, lp, 16, 0, 0);
}

// ---------------- phase-preserving RMS norm: h[BT,D,2] -> xn[BT, 512] bf16 ([xr|xi])
__global__ __launch_bounds__(256)
void norm_kernel(const float* __restrict__ h, const float* __restrict__ g,
                 ushort* __restrict__ xn)
{
    const int bt = blockIdx.x;
    const int d  = threadIdx.x;
    const float2 v = reinterpret_cast<const float2*>(h)[(size_t)bt*Dn + d];
    float sum = v.x*v.x + v.y*v.y;
    #pragma unroll
    for (int o = 32; o > 0; o >>= 1) sum += __shfl_down(sum, o);
    __shared__ float ws4[4];
    if ((threadIdx.x & 63) == 0) ws4[threadIdx.x >> 6] = sum;
    __syncthreads();
    const float tot = ws4[0] + ws4[1] + ws4[2] + ws4[3];
    const float rms = sqrtf(tot * (1.0f/Dn) + 1e-6f);
    const float scale = g[d] / rms;
    xn[(size_t)bt*512 + d]       = f2bf(v.x * scale);
    xn[(size_t)bt*512 + 256 + d] = f2bf(v.y * scale);
}

// ---------------- final norm, writes interleaved fp32 output
__global__ __launch_bounds__(256)
void out_norm_kernel(const float* __restrict__ h, const float* __restrict__ g,
                     float* __restrict__ out)
{
    const int bt = blockIdx.x;
    const int d  = threadIdx.x;
    const float2 v = reinterpret_cast<const float2*>(h)[(size_t)bt*Dn + d];
    float sum = v.x*v.x + v.y*v.y;
    #pragma unroll
    for (int o = 32; o > 0; o >>= 1) sum += __shfl_down(sum, o);
    __shared__ float ws4[4];
    if ((threadIdx.x & 63) == 0) ws4[threadIdx.x >> 6] = sum;
    __syncthreads();
    const float tot = ws4[0] + ws4[1] + ws4[2] + ws4[3];
    const float rms = sqrtf(tot * (1.0f/Dn) + 1e-6f);
    const float scale = g[d] / rms;
    float2 o; o.x = v.x * scale; o.y = v.y * scale;
    reinterpret_cast<float2*>(out)[(size_t)bt*Dn + d] = o;
}

// ---------------- bf16 MFMA GEMM: C[M,N](fp32,ldc) = A[M,K]bf16 @ Wt[N,K]bf16^T
// optional bias[N], sigmoid on cols [sig_lo,sig_hi), optional accumulate.
// BM=BN=128, BK=32, 256 threads (4 waves, 2x2 of 64x64), m97 structure.
__global__ __launch_bounds__(256)
void gemm_mfma(const ushort* __restrict__ A, const ushort* __restrict__ Wt,
               float* __restrict__ Cp, const float* __restrict__ bias,
               const int M, const int N, const int K, const int ldc,
               const int sig_lo, const int sig_hi, const int accum)
{
    __shared__ __align__(16) ushort As[128*32];
    __shared__ __align__(16) ushort Ws[128*32];
    const int tid  = threadIdx.x;
    const int lane = tid & 63;
    const int w    = tid >> 6;
    const int row0 = blockIdx.y*128, col0 = blockIdx.x*128;
    const int wr = (w >> 1)*64, wc = (w & 1)*64;
    const int l15 = lane & 15, lk8 = (lane >> 4)*8;

    // staging coords: round j covers rows [j*64, j*64+64), 4 lanes x 8 bf16 per row
    const int sr = tid >> 2;
    const int sc = (tid & 3)*8;
    const int ldsw = (tid & 192)*16;   // wave-uniform byte offset into each 4KB round

    f32x4 acc[4][4] = {};

    for (int k0 = 0; k0 < K; k0 += 32) {
        gload16(A  + (size_t)(row0 +      sr)*K + k0 + sc, (char*)As + ldsw);
        gload16(A  + (size_t)(row0 + 64 + sr)*K + k0 + sc, (char*)As + 4096 + ldsw);
        gload16(Wt + (size_t)(col0 +      sr)*K + k0 + sc, (char*)Ws + ldsw);
        gload16(Wt + (size_t)(col0 + 64 + sr)*K + k0 + sc, (char*)Ws + 4096 + ldsw);
        __syncthreads();   // drains vmcnt -> tiles resident

        bf16x8 af[4], bfr[4];
        #pragma unroll
        for (int m = 0; m < 4; ++m)
            af[m] = *(const bf16x8*)(As + (wr + m*16 + l15)*32 + lk8);
        #pragma unroll
        for (int n = 0; n < 4; ++n)
            bfr[n] = *(const bf16x8*)(Ws + (wc + n*16 + l15)*32 + lk8);
        #pragma unroll
        for (int m = 0; m < 4; ++m)
            #pragma unroll
            for (int n = 0; n < 4; ++n)
                acc[m][n] = __builtin_amdgcn_mfma_f32_16x16x32_bf16(af[m], bfr[n], acc[m][n], 0, 0, 0);
        __syncthreads();   // protect LDS before next stage
    }

    const int rbase = (lane >> 4)*4;
    #pragma unroll
    for (int m = 0; m < 4; ++m) {
        #pragma unroll
        for (int n = 0; n < 4; ++n) {
            const int gcol = col0 + wc + n*16 + l15;
            const float badd = bias ? bias[gcol] : 0.0f;
            const bool sg = (gcol >= sig_lo) && (gcol < sig_hi);
            #pragma unroll
            for (int r = 0; r < 4; ++r) {
                const int grow = row0 + wr + m*16 + rbase + r;
                float v = acc[m][n][r] + badd;
                if (sg) v = 1.0f/(1.0f + __expf(-v));
                float* cp = Cp + (size_t)grow*ldc + gcol;
                if (accum) v += *cp;
                *cp = v;
            }
        }
    }
}

// ---------------- scan pass 1: per-chunk local scan (h_start=0), in-place in z cols [0,1024)
// z layout per row (BT x 2048): [bx_r(512) | bx_i(512) | gate(512) | dx(512)]
__global__ __launch_bounds__(256)
void scan_local(float* __restrict__ z, const float* __restrict__ theta,
                const float* __restrict__ dp, float4* __restrict__ PH)
{
    const int c = blockIdx.x, b = blockIdx.y;
    const int s = blockIdx.z*256 + threadIdx.x;
    const float th = theta[s], ct = cosf(th), st = sinf(th);
    const float damp = 0.5f + 0.5f/(1.0f + __expf(-dp[s]));
    float hr = 0.f, hi = 0.f, Pr = 1.f, Pi = 0.f;
    const int t0 = c*TC;
    for (int t = 0; t < TC; ++t) {
        float* row = z + (size_t)(b*Tn + t0 + t)*2048;
        const float br = row[s], bi = row[512+s], g = row[1024+s];
        const float m = (1.0f - g)*damp;
        const float rr = ct*hr - st*hi, ri = st*hr + ct*hi;
        hr = g*br + m*rr;  hi = g*bi + m*ri;
        const float pr2 = m*(ct*Pr - st*Pi), pi2 = m*(st*Pr + ct*Pi);
        Pr = pr2; Pi = pi2;
        row[s] = hr; row[512+s] = hi;
    }
    PH[((size_t)c*Bn + b)*Sn + s] = make_float4(Pr, Pi, hr, hi);
}

// ---------------- scan pass 2: sequential combine across chunks (tiny)
__global__ __launch_bounds__(256)
void scan_combine(const float4* __restrict__ PH, const float* __restrict__ h0,
                  float2* __restrict__ cin)
{
    const int idx = blockIdx.x*256 + threadIdx.x;   // b*S + s
    const int b = idx / Sn, s = idx % Sn;
    float cr = h0[(size_t)idx*2], ci = h0[(size_t)idx*2 + 1];
    for (int c = 0; c < CHK; ++c) {
        const size_t o = ((size_t)c*Bn + b)*Sn + s;
        cin[o] = make_float2(cr, ci);
        const float4 ph = PH[o];
        const float nr = ph.z + ph.x*cr - ph.y*ci;
        const float ni = ph.w + ph.y*cr + ph.x*ci;
        cr = nr; ci = ni;
    }
}

// ---------------- scan pass 3: h_final = h_local + prefix(a)*carry_in; write bf16 [hs_r|hs_i]
__global__ __launch_bounds__(256)
void scan_fix(const float* __restrict__ z, const float* __restrict__ theta,
              const float* __restrict__ dp, const float2* __restrict__ cin,
              ushort* __restrict__ hsb)
{
    const int c = blockIdx.x, b = blockIdx.y;
    const int s = blockIdx.z*256 + threadIdx.x;
    const float th = theta[s], ct = cosf(th), st = sinf(th);
    const float damp = 0.5f + 0.5f/(1.0f + __expf(-dp[s]));
    const float2 pf = cin[((size_t)c*Bn + b)*Sn + s];
    float pr = pf.x, pi = pf.y;
    const int t0 = c*TC;
    for (int t = 0; t < TC; ++t) {
        const float* row = z + (size_t)(b*Tn + t0 + t)*2048;
        const float g = row[1024+s];
        const float m = (1.0f - g)*damp;
        const float r2 = m*(ct*pr - st*pi), i2 = m*(st*pr + ct*pi);
        pr = r2; pi = i2;
        const float hr = row[s] + pr, hi = row[512+s] + pi;
        ushort* hrow = hsb + (size_t)(b*Tn + t0 + t)*1024;
        hrow[s]       = f2bf(hr);
        hrow[512 + s] = f2bf(hi);
    }
}

// ---------------- residual: h += 0.1*((1+yr)*y), y = z cols [1536,2048)
__global__ __launch_bounds__(256)
void resid_kernel(float* __restrict__ h, const float* __restrict__ z)
{
    const size_t idx = (size_t)blockIdx.x*256 + threadIdx.x;  // row*256 + d
    const size_t row = idx >> 8;
    const int d = (int)(idx & 255);
    const float yr = z[row*2048 + 1536 + d];
    const float yi = z[row*2048 + 1792 + d];
    float2* hp = reinterpret_cast<float2*>(h);
    float2 v = hp[idx];
    v.x += 0.1f*(yr*yr + yr);
    v.y += 0.1f*(yr*yi + yi);
    hp[idx] = v;
}

// ---------------- weight prep: W1t[N=2048][K=512] (bf16, N-major = B^T layout)
__global__ __launch_bounds__(256)
void prep_w1(const float* __restrict__ Bwr, const float* __restrict__ Bwi,
             const float* __restrict__ Dwr, const float* __restrict__ Dwi,
             const float* __restrict__ Gw, ushort* __restrict__ W1t)
{
    const int l = blockIdx.y;
    const int idx = blockIdx.x*256 + threadIdx.x;   // n*512 + k
    const int n = idx >> 9, k = idx & 511;
    const float* bwr = Bwr + (size_t)l*Dn*Sn;
    const float* bwi = Bwi + (size_t)l*Dn*Sn;
    const float* dwr = Dwr + (size_t)l*Dn*Dn;
    const float* dwi = Dwi + (size_t)l*Dn*Dn;
    const float* gw  = Gw  + (size_t)l*2*Dn*Sn;
    float v;
    if (n < 512)        { const int s = n;      v = (k < 256) ? bwr[k*Sn + s] : -bwi[(k-256)*Sn + s]; }
    else if (n < 1024)  { const int s = n-512;  v = (k < 256) ? bwi[k*Sn + s] :  bwr[(k-256)*Sn + s]; }
    else if (n < 1536)  { const int s = n-1024; v = gw[(size_t)k*Sn + s]; }
    else if (n < 1792)  { const int d = n-1536; v = (k < 256) ? dwr[k*Dn + d] : -dwi[(k-256)*Dn + d]; }
    else                { const int d = n-1792; v = (k < 256) ? dwi[k*Dn + d] :  dwr[(k-256)*Dn + d]; }
    W1t[(size_t)l*2048*512 + idx] = f2bf(v);
}

// ---------------- weight prep: W2t[N=512][K=1024]
__global__ __launch_bounds__(256)
void prep_w2(const float* __restrict__ Cwr, const float* __restrict__ Cwi,
             ushort* __restrict__ W2t)
{
    const int l = blockIdx.y;
    const int idx = blockIdx.x*256 + threadIdx.x;   // n*1024 + k
    const int n = idx >> 10, k = idx & 1023;
    const float* cwr = Cwr + (size_t)l*Sn*Dn;
    const float* cwi = Cwi + (size_t)l*Sn*Dn;
    float v;
    if (n < 256) { const int d = n;     v = (k < 512) ? cwr[k*Dn + d] : -cwi[(k-512)*Dn + d]; }
    else         { const int d = n-256; v = (k < 512) ? cwi[k*Dn + d] :  cwr[(k-512)*Dn + d]; }
    W2t[(size_t)l*512*1024 + idx] = f2bf(v);
}

// ---------------- bias prep: full 2048-wide bias (gate bias in cols [1024,1536))
__global__ __launch_bounds__(256)
void prep_bias(const float* __restrict__ gb, float* __restrict__ biasf)
{
    const int l = blockIdx.y;
    const int n = blockIdx.x*256 + threadIdx.x;
    biasf[(size_t)l*2048 + n] = (n >= 1024 && n < 1536) ? gb[(size_t)l*Sn + n - 1024] : 0.0f;
}

extern "C" void kernel_launch(void* const* d_in, const int* in_sizes, int n_in,
                              void* d_out, int out_size, void* d_ws, size_t ws_size,
                              hipStream_t stream)
{
    const float* x      = (const float*)d_in[0];
    const float* h0     = (const float*)d_in[1];
    const float* theta  = (const float*)d_in[2];
    const float* dp     = (const float*)d_in[3];
    const float* B_wr   = (const float*)d_in[4];
    const float* B_wi   = (const float*)d_in[5];
    const float* C_wr   = (const float*)d_in[6];
    const float* C_wi   = (const float*)d_in[7];
    const float* D_wr   = (const float*)d_in[8];
    const float* D_wi   = (const float*)d_in[9];
    const float* gate_w = (const float*)d_in[10];
    const float* gate_b = (const float*)d_in[11];
    const float* norm_g = (const float*)d_in[12];
    const float* out_g  = (const float*)d_in[13];
    float* out = (float*)d_out;

    char* w = (char*)d_ws;
    float*  z     = (float*)w;   w += (size_t)BT*2048*4;      // 64 MB
    float*  h     = (float*)w;   w += (size_t)BT*512*4;       // 16 MB
    float*  biasf = (float*)w;   w += (size_t)8*2048*4;       // 64 KB
    float4* PH    = (float4*)w;  w += (size_t)CHK*Bn*Sn*16;   // 1 MB
    float2* cin   = (float2*)w;  w += (size_t)CHK*Bn*Sn*8;    // 0.5 MB
    ushort* xn    = (ushort*)w;  w += (size_t)BT*512*2;       // 8 MB
    ushort* hsb   = (ushort*)w;  w += (size_t)BT*1024*2;      // 16 MB
    ushort* W1t   = (ushort*)w;  w += (size_t)Lnum*2048*512*2;// 16 MB
    ushort* W2t   = (ushort*)w;  w += (size_t)Lnum*512*1024*2;// 8 MB

    // residual stream
    hipMemcpyAsync(h, x, sizeof(float)*(size_t)BT*Dn*2, hipMemcpyDeviceToDevice, stream);

    // weight prep (all layers, once per call)
    prep_w1<<<dim3(2048*512/256, Lnum), 256, 0, stream>>>(B_wr, B_wi, D_wr, D_wi, gate_w, W1t);
    prep_w2<<<dim3(512*1024/256, Lnum), 256, 0, stream>>>(C_wr, C_wi, W2t);
    prep_bias<<<dim3(8, Lnum), 256, 0, stream>>>(gate_b, biasf);

    const dim3 g1(2048/128, BT/128);  // (16,64)
    const dim3 g2(512/128,  BT/128);  // (4,64)
    const dim3 gs(CHK, Bn, Sn/256);   // (32,4,2)

    for (int l = 0; l < Lnum; ++l) {
        norm_kernel<<<BT, 256, 0, stream>>>(h, norm_g + (size_t)l*Dn, xn);

        // z = xn @ W_all  ->  [bx_r | bx_i | sigmoid(gate) | dx_r | dx_i]
        gemm_mfma<<<g1, 256, 0, stream>>>(xn, W1t + (size_t)l*2048*512, z,
                                          biasf + (size_t)l*2048,
                                          BT, 2048, 512, 2048, 1024, 1536, 0);

        scan_local<<<gs, 256, 0, stream>>>(z, theta + (size_t)l*Sn, dp + (size_t)l*Sn, PH);
        scan_combine<<<(Bn*Sn)/256, 256, 0, stream>>>(PH, h0 + (size_t)l*Bn*Sn*2, cin);
        scan_fix<<<gs, 256, 0, stream>>>(z, theta + (size_t)l*Sn, dp + (size_t)l*Sn, cin, hsb);

        // z[:,1536:2048] += hsb @ Wc   (y = ch + dx)
        gemm_mfma<<<g2, 256, 0, stream>>>(hsb, W2t + (size_t)l*512*1024, z + 1536,
                                          nullptr, BT, 512, 1024, 2048, 1<<30, 1<<30, 1);

        resid_kernel<<<(size_t)BT*Dn/256, 256, 0, stream>>>(h, z);
    }

    out_norm_kernel<<<BT, 256, 0, stream>>>(h, out_g, out);
}

// Round 3
// 769.432 us; speedup vs baseline: 9.0828x; 1.4682x over previous
//
#include <hip/hip_runtime.h>
#include <math.h>

#define Lnum 8
#define Bn 4
#define Tn 2048
#define Dn 256
#define Sn 512
#define BT (Bn*Tn)      // 8192
#define CHK 32
#define TC (Tn/CHK)     // 64

typedef __attribute__((ext_vector_type(8))) short bf16x8;
typedef __attribute__((ext_vector_type(4))) float f32x4;

__device__ __forceinline__ ushort f2bf(float f) {
    union { float f; unsigned u; } v; v.f = f;
    unsigned r = v.u + 0x7fffu + ((v.u >> 16) & 1u);   // RNE
    return (ushort)(r >> 16);
}
__device__ __forceinline__ float bf2f(ushort u) {
    union { unsigned u; float f; } v; v.u = ((unsigned)u) << 16; return v.f;
}

// direct global->LDS async copy, 16B per lane (dest = wave-uniform base + lane*16)
__device__ __forceinline__ void gload16(const void* g, void* l) {
    using u32 = unsigned int;
    auto gp = (const __attribute__((address_space(1))) u32*)(uintptr_t)g;
    auto lp = (__attribute__((address_space(3))) u32*)(uintptr_t)l;
    __builtin_amdgcn_global_load_lds(gp, lp, 16, 0, 0);
}

// ---------------- phase-preserving RMS norm: h[BT,D,2] -> xn[BT,512] bf16 ([xr|xi])
__global__ __launch_bounds__(256)
void norm_kernel(const float* __restrict__ h, const float* __restrict__ g,
                 ushort* __restrict__ xn)
{
    const int bt = blockIdx.x;
    const int d  = threadIdx.x;
    const float2 v = reinterpret_cast<const float2*>(h)[(size_t)bt*Dn + d];
    float sum = v.x*v.x + v.y*v.y;
    #pragma unroll
    for (int o = 32; o > 0; o >>= 1) sum += __shfl_down(sum, o);
    __shared__ float ws4[4];
    if ((threadIdx.x & 63) == 0) ws4[threadIdx.x >> 6] = sum;
    __syncthreads();
    const float tot = ws4[0] + ws4[1] + ws4[2] + ws4[3];
    const float rms = sqrtf(tot * (1.0f/Dn) + 1e-6f);
    const float scale = g[d] / rms;
    xn[(size_t)bt*512 + d]       = f2bf(v.x * scale);
    xn[(size_t)bt*512 + 256 + d] = f2bf(v.y * scale);
}

// ---------------- final norm, fp32 interleaved output
__global__ __launch_bounds__(256)
void out_norm_kernel(const float* __restrict__ h, const float* __restrict__ g,
                     float* __restrict__ out)
{
    const int bt = blockIdx.x;
    const int d  = threadIdx.x;
    const float2 v = reinterpret_cast<const float2*>(h)[(size_t)bt*Dn + d];
    float sum = v.x*v.x + v.y*v.y;
    #pragma unroll
    for (int o = 32; o > 0; o >>= 1) sum += __shfl_down(sum, o);
    __shared__ float ws4[4];
    if ((threadIdx.x & 63) == 0) ws4[threadIdx.x >> 6] = sum;
    __syncthreads();
    const float tot = ws4[0] + ws4[1] + ws4[2] + ws4[3];
    const float rms = sqrtf(tot * (1.0f/Dn) + 1e-6f);
    const float scale = g[d] / rms;
    float2 o; o.x = v.x * scale; o.y = v.y * scale;
    reinterpret_cast<float2*>(out)[(size_t)bt*Dn + d] = o;
}

// ======== GEMM1: zb[8192,2048]bf16 = xn[8192,512] @ W1t^T; bias+sigmoid on [1024,1536)
// 128x128 tile, BK=32, 2-phase dbuf LDS, XCD-swizzled block order.
__global__ __launch_bounds__(256)
void gemm1_kernel(const ushort* __restrict__ A, const ushort* __restrict__ Wt,
                  ushort* __restrict__ Cb, const float* __restrict__ bias)
{
    constexpr int K = 512, NT = K/32, NBX = 16, NWG = 16*64;
    __shared__ __align__(16) ushort As[2][128*32];
    __shared__ __align__(16) ushort Ws[2][128*32];
    const int tid = threadIdx.x, lane = tid & 63, w = tid >> 6;
    int lin = blockIdx.y * gridDim.x + blockIdx.x;
    lin = (lin & 7) * (NWG >> 3) + (lin >> 3);          // XCD-contiguous chunks
    const int row0 = (lin / NBX) * 128, col0 = (lin % NBX) * 128;
    const int wr = (w >> 1)*64, wc = (w & 1)*64;
    const int l15 = lane & 15, lk8 = (lane >> 4)*8;
    const int sr = tid >> 2, sc = (tid & 3)*8;
    const int ldsw = (tid & 192)*16;                    // wave-uniform 1KB chunk

    f32x4 acc[4][4] = {};

#define STG1(bf, k0) do{ \
    gload16(A  + (size_t)(row0      + sr)*K + (k0) + sc, (char*)As[bf] + ldsw); \
    gload16(A  + (size_t)(row0 + 64 + sr)*K + (k0) + sc, (char*)As[bf] + 4096 + ldsw); \
    gload16(Wt + (size_t)(col0      + sr)*K + (k0) + sc, (char*)Ws[bf] + ldsw); \
    gload16(Wt + (size_t)(col0 + 64 + sr)*K + (k0) + sc, (char*)Ws[bf] + 4096 + ldsw); }while(0)

    STG1(0, 0);
    __syncthreads();
    int cur = 0;
    for (int t = 0; t < NT; ++t) {
        if (t + 1 < NT) STG1(cur ^ 1, (t+1)*32);
        bf16x8 af[4], bw[4];
        #pragma unroll
        for (int m = 0; m < 4; ++m) af[m] = *(const bf16x8*)(As[cur] + (wr + m*16 + l15)*32 + lk8);
        #pragma unroll
        for (int n = 0; n < 4; ++n) bw[n] = *(const bf16x8*)(Ws[cur] + (wc + n*16 + l15)*32 + lk8);
        #pragma unroll
        for (int m = 0; m < 4; ++m)
            #pragma unroll
            for (int n = 0; n < 4; ++n)
                acc[m][n] = __builtin_amdgcn_mfma_f32_16x16x32_bf16(af[m], bw[n], acc[m][n], 0, 0, 0);
        __syncthreads();
        cur ^= 1;
    }
#undef STG1

    const int rbase = (lane >> 4)*4;
    #pragma unroll
    for (int m = 0; m < 4; ++m) {
        #pragma unroll
        for (int n = 0; n < 4; ++n) {
            const int gcol = col0 + wc + n*16 + l15;
            const float badd = bias[gcol];
            const bool sg = (gcol >= 1024) && (gcol < 1536);
            #pragma unroll
            for (int r = 0; r < 4; ++r) {
                const int grow = row0 + wr + m*16 + rbase + r;
                float v = acc[m][n][r] + badd;
                if (sg) v = 1.0f/(1.0f + __expf(-v));
                Cb[(size_t)grow*2048 + gcol] = f2bf(v);
            }
        }
    }
}

// ======== GEMM2: y = hsb[8192,1024] @ W2t^T + dx(zb cols 1536+), interleaved (yr,yi) pairs,
// fused residual: h[row, col] += 0.1*(yr*y + y). 128x128 tile, BK=32, dbuf.
__global__ __launch_bounds__(256)
void gemm2_kernel(const ushort* __restrict__ A, const ushort* __restrict__ Wt,
                  const ushort* __restrict__ zb, float* __restrict__ h)
{
    constexpr int K = 1024, NT = K/32, NBX = 4, NWG = 4*64;
    __shared__ __align__(16) ushort As[2][128*32];
    __shared__ __align__(16) ushort Ws[2][128*32];
    const int tid = threadIdx.x, lane = tid & 63, w = tid >> 6;
    int lin = blockIdx.y * gridDim.x + blockIdx.x;
    lin = (lin & 7) * (NWG >> 3) + (lin >> 3);
    const int row0 = (lin / NBX) * 128, col0 = (lin % NBX) * 128;
    const int wr = (w >> 1)*64, wc = (w & 1)*64;
    const int l15 = lane & 15, lk8 = (lane >> 4)*8;
    const int sr = tid >> 2, sc = (tid & 3)*8;
    const int ldsw = (tid & 192)*16;

    f32x4 acc[4][4] = {};

#define STG2(bf, k0) do{ \
    gload16(A  + (size_t)(row0      + sr)*K + (k0) + sc, (char*)As[bf] + ldsw); \
    gload16(A  + (size_t)(row0 + 64 + sr)*K + (k0) + sc, (char*)As[bf] + 4096 + ldsw); \
    gload16(Wt + (size_t)(col0      + sr)*K + (k0) + sc, (char*)Ws[bf] + ldsw); \
    gload16(Wt + (size_t)(col0 + 64 + sr)*K + (k0) + sc, (char*)Ws[bf] + 4096 + ldsw); }while(0)

    STG2(0, 0);
    __syncthreads();
    int cur = 0;
    for (int t = 0; t < NT; ++t) {
        if (t + 1 < NT) STG2(cur ^ 1, (t+1)*32);
        bf16x8 af[4], bw[4];
        #pragma unroll
        for (int m = 0; m < 4; ++m) af[m] = *(const bf16x8*)(As[cur] + (wr + m*16 + l15)*32 + lk8);
        #pragma unroll
        for (int n = 0; n < 4; ++n) bw[n] = *(const bf16x8*)(Ws[cur] + (wc + n*16 + l15)*32 + lk8);
        #pragma unroll
        for (int m = 0; m < 4; ++m)
            #pragma unroll
            for (int n = 0; n < 4; ++n)
                acc[m][n] = __builtin_amdgcn_mfma_f32_16x16x32_bf16(af[m], bw[n], acc[m][n], 0, 0, 0);
        __syncthreads();
        cur ^= 1;
    }
#undef STG2

    const int rbase = (lane >> 4)*4;
    #pragma unroll
    for (int m = 0; m < 4; ++m) {
        #pragma unroll
        for (int n = 0; n < 4; ++n) {
            const int gcol = col0 + wc + n*16 + l15;   // parity(gcol) == parity(lane)
            #pragma unroll
            for (int r = 0; r < 4; ++r) {
                const int grow = row0 + wr + m*16 + rbase + r;
                float v = acc[m][n][r] + bf2f(zb[(size_t)grow*2048 + 1536 + gcol]);
                const float p = __shfl_xor(v, 1);
                const float yr = (gcol & 1) ? p : v;
                h[(size_t)grow*512 + gcol] += 0.1f*(yr*v + v);
            }
        }
    }
}

// ---------------- scan pass 1: per-chunk (P, h_end) with h_start=0 (read-only over zb)
__global__ __launch_bounds__(256)
void scan_part1(const ushort* __restrict__ zb, const float* __restrict__ theta,
                const float* __restrict__ dp, float4* __restrict__ PH)
{
    const int c = blockIdx.x, b = blockIdx.y;
    const int s = blockIdx.z*256 + threadIdx.x;
    const float th = theta[s], ct = cosf(th), st = sinf(th);
    const float damp = 0.5f + 0.5f/(1.0f + __expf(-dp[s]));
    float hr = 0.f, hi = 0.f, Pr = 1.f, Pi = 0.f;
    const ushort* row = zb + (size_t)(b*Tn + c*TC)*2048;
    for (int t = 0; t < TC; ++t, row += 2048) {
        const float br = bf2f(row[s]), bi = bf2f(row[512+s]), g = bf2f(row[1024+s]);
        const float mm = (1.0f - g)*damp;
        const float mc = mm*ct, ms = mm*st;
        const float rr = mc*hr - ms*hi, ri = ms*hr + mc*hi;
        hr = g*br + rr;  hi = g*bi + ri;
        const float pr = mc*Pr - ms*Pi, pi = ms*Pr + mc*Pi;
        Pr = pr; Pi = pi;
    }
    PH[((size_t)c*Bn + b)*Sn + s] = make_float4(Pr, Pi, hr, hi);
}

// ---------------- scan pass 2: sequential combine across chunks (tiny)
__global__ __launch_bounds__(256)
void scan_combine(const float4* __restrict__ PH, const float* __restrict__ h0,
                  float2* __restrict__ cin)
{
    const int idx = blockIdx.x*256 + threadIdx.x;   // b*S + s
    const int b = idx / Sn, s = idx % Sn;
    float cr = h0[(size_t)idx*2], ci = h0[(size_t)idx*2 + 1];
    for (int c = 0; c < CHK; ++c) {
        const size_t o = ((size_t)c*Bn + b)*Sn + s;
        cin[o] = make_float2(cr, ci);
        const float4 ph = PH[o];
        const float nr = ph.z + ph.x*cr - ph.y*ci;
        const float ni = ph.w + ph.y*cr + ph.x*ci;
        cr = nr; ci = ni;
    }
}

// ---------------- scan pass 3: exact scan with carry-in, write bf16 [hs_r|hs_i]
__global__ __launch_bounds__(256)
void scan_apply(const ushort* __restrict__ zb, const float* __restrict__ theta,
                const float* __restrict__ dp, const float2* __restrict__ cin,
                ushort* __restrict__ hsb)
{
    const int c = blockIdx.x, b = blockIdx.y;
    const int s = blockIdx.z*256 + threadIdx.x;
    const float th = theta[s], ct = cosf(th), st = sinf(th);
    const float damp = 0.5f + 0.5f/(1.0f + __expf(-dp[s]));
    const float2 c0 = cin[((size_t)c*Bn + b)*Sn + s];
    float hr = c0.x, hi = c0.y;
    const ushort* row = zb + (size_t)(b*Tn + c*TC)*2048;
    ushort* hrow = hsb + (size_t)(b*Tn + c*TC)*1024;
    for (int t = 0; t < TC; ++t, row += 2048, hrow += 1024) {
        const float br = bf2f(row[s]), bi = bf2f(row[512+s]), g = bf2f(row[1024+s]);
        const float mm = (1.0f - g)*damp;
        const float mc = mm*ct, ms = mm*st;
        const float rr = mc*hr - ms*hi, ri = ms*hr + mc*hi;
        hr = g*br + rr;  hi = g*bi + ri;
        hrow[s]       = f2bf(hr);
        hrow[512 + s] = f2bf(hi);
    }
}

// ---------------- weight prep: W1t[2048][512] bf16; dx cols interleaved (yr,yi)
__global__ __launch_bounds__(256)
void prep_w1(const float* __restrict__ Bwr, const float* __restrict__ Bwi,
             const float* __restrict__ Dwr, const float* __restrict__ Dwi,
             const float* __restrict__ Gw, ushort* __restrict__ W1t)
{
    const int l = blockIdx.y;
    const int idx = blockIdx.x*256 + threadIdx.x;   // n*512 + k
    const int n = idx >> 9, k = idx & 511;
    const float* bwr = Bwr + (size_t)l*Dn*Sn;
    const float* bwi = Bwi + (size_t)l*Dn*Sn;
    const float* dwr = Dwr + (size_t)l*Dn*Dn;
    const float* dwi = Dwi + (size_t)l*Dn*Dn;
    const float* gw  = Gw  + (size_t)l*2*Dn*Sn;
    float v;
    if (n < 512)        { const int s = n;      v = (k < 256) ? bwr[k*Sn + s] : -bwi[(k-256)*Sn + s]; }
    else if (n < 1024)  { const int s = n-512;  v = (k < 256) ? bwi[k*Sn + s] :  bwr[(k-256)*Sn + s]; }
    else if (n < 1536)  { const int s = n-1024; v = gw[(size_t)k*Sn + s]; }
    else {
        const int j = n - 1536, d = j >> 1;
        if ((j & 1) == 0) v = (k < 256) ? dwr[k*Dn + d] : -dwi[(k-256)*Dn + d];
        else              v = (k < 256) ? dwi[k*Dn + d] :  dwr[(k-256)*Dn + d];
    }
    W1t[(size_t)l*2048*512 + idx] = f2bf(v);
}

// ---------------- weight prep: W2t[512][1024] bf16, output cols interleaved (yr,yi)
__global__ __launch_bounds__(256)
void prep_w2(const float* __restrict__ Cwr, const float* __restrict__ Cwi,
             ushort* __restrict__ W2t)
{
    const int l = blockIdx.y;
    const int idx = blockIdx.x*256 + threadIdx.x;   // n*1024 + k
    const int n = idx >> 10, k = idx & 1023;
    const float* cwr = Cwr + (size_t)l*Sn*Dn;
    const float* cwi = Cwi + (size_t)l*Sn*Dn;
    const int d = n >> 1;
    float v;
    if ((n & 1) == 0) v = (k < 512) ? cwr[k*Dn + d] : -cwi[(k-512)*Dn + d];
    else              v = (k < 512) ? cwi[k*Dn + d] :  cwr[(k-512)*Dn + d];
    W2t[(size_t)l*512*1024 + idx] = f2bf(v);
}

// ---------------- bias prep
__global__ __launch_bounds__(256)
void prep_bias(const float* __restrict__ gb, float* __restrict__ biasf)
{
    const int l = blockIdx.y;
    const int n = blockIdx.x*256 + threadIdx.x;
    biasf[(size_t)l*2048 + n] = (n >= 1024 && n < 1536) ? gb[(size_t)l*Sn + n - 1024] : 0.0f;
}

extern "C" void kernel_launch(void* const* d_in, const int* in_sizes, int n_in,
                              void* d_out, int out_size, void* d_ws, size_t ws_size,
                              hipStream_t stream)
{
    const float* x      = (const float*)d_in[0];
    const float* h0     = (const float*)d_in[1];
    const float* theta  = (const float*)d_in[2];
    const float* dp     = (const float*)d_in[3];
    const float* B_wr   = (const float*)d_in[4];
    const float* B_wi   = (const float*)d_in[5];
    const float* C_wr   = (const float*)d_in[6];
    const float* C_wi   = (const float*)d_in[7];
    const float* D_wr   = (const float*)d_in[8];
    const float* D_wi   = (const float*)d_in[9];
    const float* gate_w = (const float*)d_in[10];
    const float* gate_b = (const float*)d_in[11];
    const float* norm_g = (const float*)d_in[12];
    const float* out_g  = (const float*)d_in[13];
    float* out = (float*)d_out;

    char* w = (char*)d_ws;
    float*  h     = (float*)w;   w += (size_t)BT*512*4;        // 16 MB
    float*  biasf = (float*)w;   w += (size_t)8*2048*4;        // 64 KB
    float4* PH    = (float4*)w;  w += (size_t)CHK*Bn*Sn*16;    // 1 MB
    float2* cin   = (float2*)w;  w += (size_t)CHK*Bn*Sn*8;     // 0.5 MB
    ushort* zb    = (ushort*)w;  w += (size_t)BT*2048*2;       // 32 MB
    ushort* xn    = (ushort*)w;  w += (size_t)BT*512*2;        // 8 MB
    ushort* hsb   = (ushort*)w;  w += (size_t)BT*1024*2;       // 16 MB
    ushort* W1t   = (ushort*)w;  w += (size_t)Lnum*2048*512*2; // 16 MB
    ushort* W2t   = (ushort*)w;  w += (size_t)Lnum*512*1024*2; // 8 MB

    hipMemcpyAsync(h, x, sizeof(float)*(size_t)BT*Dn*2, hipMemcpyDeviceToDevice, stream);

    prep_w1<<<dim3(2048*512/256, Lnum), 256, 0, stream>>>(B_wr, B_wi, D_wr, D_wi, gate_w, W1t);
    prep_w2<<<dim3(512*1024/256, Lnum), 256, 0, stream>>>(C_wr, C_wi, W2t);
    prep_bias<<<dim3(8, Lnum), 256, 0, stream>>>(gate_b, biasf);

    const dim3 g1(16, 64);
    const dim3 g2(4, 64);
    const dim3 gs(CHK, Bn, Sn/256);

    for (int l = 0; l < Lnum; ++l) {
        norm_kernel<<<BT, 256, 0, stream>>>(h, norm_g + (size_t)l*Dn, xn);

        gemm1_kernel<<<g1, 256, 0, stream>>>(xn, W1t + (size_t)l*2048*512, zb,
                                             biasf + (size_t)l*2048);

        scan_part1<<<gs, 256, 0, stream>>>(zb, theta + (size_t)l*Sn, dp + (size_t)l*Sn, PH);
        scan_combine<<<(Bn*Sn)/256, 256, 0, stream>>>(PH, h0 + (size_t)l*Bn*Sn*2, cin);
        scan_apply<<<gs, 256, 0, stream>>>(zb, theta + (size_t)l*Sn, dp + (size_t)l*Sn, cin, hsb);

        gemm2_kernel<<<g2, 256, 0, stream>>>(hsb, W2t + (size_t)l*512*1024, zb, h);
    }

    out_norm_kernel<<<BT, 256, 0, stream>>>(h, out_g, out);
}

// Round 4
// 752.734 us; speedup vs baseline: 9.2843x; 1.0222x over previous
//
#include <hip/hip_runtime.h>
#include <math.h>

#define Lnum 8
#define Bn 4
#define Tn 2048
#define Dn 256
#define Sn 512
#define BT (Bn*Tn)      // 8192
#define CHK 32
#define TC (Tn/CHK)     // 64

typedef __attribute__((ext_vector_type(8))) short bf16x8;
typedef __attribute__((ext_vector_type(4))) float f32x4;

__device__ __forceinline__ ushort f2bf(float f) {
    union { float f; unsigned u; } v; v.f = f;
    unsigned r = v.u + 0x7fffu + ((v.u >> 16) & 1u);   // RNE
    return (ushort)(r >> 16);
}
__device__ __forceinline__ float bf2f(ushort u) {
    union { unsigned u; float f; } v; v.u = ((unsigned)u) << 16; return v.f;
}

// direct global->LDS async copy, 16B per lane (dest = wave-uniform base + lane*16)
__device__ __forceinline__ void gload16(const void* g, void* l) {
    using u32 = unsigned int;
    auto gp = (const __attribute__((address_space(1))) u32*)(uintptr_t)g;
    auto lp = (__attribute__((address_space(3))) u32*)(uintptr_t)l;
    __builtin_amdgcn_global_load_lds(gp, lp, 16, 0, 0);
}

// ---------------- phase-preserving RMS norm: h[BT,D,2] -> xn[BT,512] bf16 ([xr|xi])
__global__ __launch_bounds__(256)
void norm_kernel(const float* __restrict__ h, const float* __restrict__ g,
                 ushort* __restrict__ xn)
{
    const int bt = blockIdx.x;
    const int d  = threadIdx.x;
    const float2 v = reinterpret_cast<const float2*>(h)[(size_t)bt*Dn + d];
    float sum = v.x*v.x + v.y*v.y;
    #pragma unroll
    for (int o = 32; o > 0; o >>= 1) sum += __shfl_down(sum, o);
    __shared__ float ws4[4];
    if ((threadIdx.x & 63) == 0) ws4[threadIdx.x >> 6] = sum;
    __syncthreads();
    const float tot = ws4[0] + ws4[1] + ws4[2] + ws4[3];
    const float rms = sqrtf(tot * (1.0f/Dn) + 1e-6f);
    const float scale = g[d] / rms;
    xn[(size_t)bt*512 + d]       = f2bf(v.x * scale);
    xn[(size_t)bt*512 + 256 + d] = f2bf(v.y * scale);
}

// ---------------- final norm, fp32 interleaved output
__global__ __launch_bounds__(256)
void out_norm_kernel(const float* __restrict__ h, const float* __restrict__ g,
                     float* __restrict__ out)
{
    const int bt = blockIdx.x;
    const int d  = threadIdx.x;
    const float2 v = reinterpret_cast<const float2*>(h)[(size_t)bt*Dn + d];
    float sum = v.x*v.x + v.y*v.y;
    #pragma unroll
    for (int o = 32; o > 0; o >>= 1) sum += __shfl_down(sum, o);
    __shared__ float ws4[4];
    if ((threadIdx.x & 63) == 0) ws4[threadIdx.x >> 6] = sum;
    __syncthreads();
    const float tot = ws4[0] + ws4[1] + ws4[2] + ws4[3];
    const float rms = sqrtf(tot * (1.0f/Dn) + 1e-6f);
    const float scale = g[d] / rms;
    float2 o; o.x = v.x * scale; o.y = v.y * scale;
    reinterpret_cast<float2*>(out)[(size_t)bt*Dn + d] = o;
}

#define PH_SYNC_IN  __builtin_amdgcn_s_barrier(); \
    asm volatile("s_waitcnt lgkmcnt(0)" ::: "memory"); \
    __builtin_amdgcn_sched_barrier(0); \
    __builtin_amdgcn_s_setprio(1);
#define PH_SYNC_OUT __builtin_amdgcn_s_setprio(0); __builtin_amdgcn_s_barrier();

// ======== GEMM1: zb[8192,2048]bf16 = xn[8192,512] @ W1t^T; bias+sigmoid on [1024,1536)
// 256x256 tile, BK=64, 8 waves (2Mx4N), 8-phase counted-vmcnt schedule, T2 swizzle.
__global__ __launch_bounds__(512, 2)
void gemm1_kernel(const ushort* __restrict__ A, const ushort* __restrict__ Wt,
                  ushort* __restrict__ Cb, const float* __restrict__ bias)
{
    constexpr int K = 512, NIT = 4;   // 8 K-tiles of 64
    __shared__ __align__(16) char lds[131072];   // 2 bufs x (A 32K + B 32K)
    const int tid = threadIdx.x, lane = tid & 63, wid = tid >> 6;
    const int wm = wid >> 2, wn = wid & 3;
    int lin = blockIdx.x;
    lin = (lin & 7) * 32 + (lin >> 3);           // XCD-contiguous chunks (256%8==0)
    const int row0 = (lin >> 3) * 256, col0 = (lin & 7) * 256;
    const int rl = lane & 15, gb = lane >> 4;
    const int pg0 = ((gb ^ (rl & 7)) << 4);      // swizzled byte offset, ks=0
    const int pg1 = (((4 + gb) ^ (rl & 7)) << 4);// ks=1
    const int srow = tid >> 3;                   // staging row within 64-row round
    const int sg   = (tid & 7) ^ (srow & 7);     // pre-swizzled source granule
    const int ldsw = wid * 1024;                 // wave-uniform chunk within round

    f32x4 acc[8][4] = {};
    bf16x8 aF[8], bF0[4], bF1[4];

#define STG_A(buf, hh, kt) do { \
    const ushort* gp_ = A + (size_t)(row0 + (hh)*128 + srow)*K + (kt)*64 + sg*8; \
    char* lp_ = lds + (buf)*65536 + (hh)*16384 + ldsw; \
    gload16(gp_, lp_); gload16(gp_ + (size_t)64*K, lp_ + 8192); } while(0)
#define STG_B(buf, hh, kt) do { \
    const ushort* gp_ = Wt + (size_t)(col0 + (hh)*128 + srow)*K + (kt)*64 + sg*8; \
    char* lp_ = lds + (buf)*65536 + 32768 + (hh)*16384 + ldsw; \
    gload16(gp_, lp_); gload16(gp_ + (size_t)64*K, lp_ + 8192); } while(0)
#define LDA(buf, Mh) { _Pragma("unroll") for (int m2 = 0; m2 < 4; ++m2) { \
    const int rb_ = (buf)*65536 + (wm*128 + (Mh)*64 + m2*16 + rl)*128; \
    aF[m2*2+0] = *(const bf16x8*)(lds + rb_ + pg0); \
    aF[m2*2+1] = *(const bf16x8*)(lds + rb_ + pg1); } }
#define LDB(buf, Nh, dst) { _Pragma("unroll") for (int n2 = 0; n2 < 2; ++n2) { \
    const int rb_ = (buf)*65536 + 32768 + (wn*64 + (Nh)*32 + n2*16 + rl)*128; \
    dst[n2*2+0] = *(const bf16x8*)(lds + rb_ + pg0); \
    dst[n2*2+1] = *(const bf16x8*)(lds + rb_ + pg1); } }
#define MM16(Mh, Nh, bsrc) { _Pragma("unroll") for (int m2 = 0; m2 < 4; ++m2) \
    _Pragma("unroll") for (int n2 = 0; n2 < 2; ++n2) { \
      acc[(Mh)*4+m2][(Nh)*2+n2] = __builtin_amdgcn_mfma_f32_16x16x32_bf16(aF[m2*2+0], bsrc[n2*2+0], acc[(Mh)*4+m2][(Nh)*2+n2], 0,0,0); \
      acc[(Mh)*4+m2][(Nh)*2+n2] = __builtin_amdgcn_mfma_f32_16x16x32_bf16(aF[m2*2+1], bsrc[n2*2+1], acc[(Mh)*4+m2][(Nh)*2+n2], 0,0,0); } }

    // prologue: K-tile0 fully + B halves of K-tile1
    STG_B(0,0,0); STG_B(0,1,0); STG_A(0,0,0); STG_A(0,1,0);
    STG_B(1,0,1); STG_B(1,1,1);
    asm volatile("s_waitcnt vmcnt(4)" ::: "memory");
    __builtin_amdgcn_s_barrier();

    for (int t = 0; t < NIT; ++t) {
        const bool last = (t == NIT-1);
        // ph1: quadrant (M0,N0) of kt0=2t (buf0)
        LDA(0,0); LDB(0,0,bF0);
        STG_A(1,0,2*t+1);
        PH_SYNC_IN; MM16(0,0,bF0); PH_SYNC_OUT;
        // ph2: (M0,N1)
        LDB(0,1,bF1);
        STG_A(1,1,2*t+1);
        PH_SYNC_IN; MM16(0,1,bF1); PH_SYNC_OUT;
        // ph3: (M1,N0)
        LDA(0,1);
        if (!last) STG_B(0,0,2*t+2);
        PH_SYNC_IN; MM16(1,0,bF0); PH_SYNC_OUT;
        // ph4: (M1,N1) + vmcnt
        if (!last) STG_B(0,1,2*t+2);
        PH_SYNC_IN; MM16(1,1,bF1);
        __builtin_amdgcn_s_setprio(0);
        if (last) { asm volatile("s_waitcnt vmcnt(0)" ::: "memory"); }
        else      { asm volatile("s_waitcnt vmcnt(4)" ::: "memory"); }
        __builtin_amdgcn_s_barrier();
        // ph5: (M0,N0) of kt1=2t+1 (buf1)
        LDA(1,0); LDB(1,0,bF0);
        if (!last) STG_A(0,0,2*t+2);
        PH_SYNC_IN; MM16(0,0,bF0); PH_SYNC_OUT;
        // ph6: (M0,N1)
        LDB(1,1,bF1);
        if (!last) STG_A(0,1,2*t+2);
        PH_SYNC_IN; MM16(0,1,bF1); PH_SYNC_OUT;
        // ph7: (M1,N0)
        LDA(1,1);
        if (!last) STG_B(1,0,2*t+3);
        PH_SYNC_IN; MM16(1,0,bF0); PH_SYNC_OUT;
        // ph8: (M1,N1) + vmcnt
        if (!last) STG_B(1,1,2*t+3);
        PH_SYNC_IN; MM16(1,1,bF1);
        __builtin_amdgcn_s_setprio(0);
        if (last) { asm volatile("s_waitcnt vmcnt(0)" ::: "memory"); }
        else      { asm volatile("s_waitcnt vmcnt(4)" ::: "memory"); }
        __builtin_amdgcn_s_barrier();
    }
#undef STG_A
#undef STG_B
#undef LDA
#undef LDB
#undef MM16

    const int rbase = (lane >> 4)*4;
    #pragma unroll
    for (int m = 0; m < 8; ++m) {
        #pragma unroll
        for (int n = 0; n < 4; ++n) {
            const int gcol = col0 + wn*64 + n*16 + rl;
            const float badd = bias[gcol];
            const bool sg2 = (gcol >= 1024) && (gcol < 1536);
            #pragma unroll
            for (int r = 0; r < 4; ++r) {
                const int grow = row0 + wm*128 + m*16 + rbase + r;
                float v = acc[m][n][r] + badd;
                if (sg2) v = 1.0f/(1.0f + __expf(-v));
                Cb[(size_t)grow*2048 + gcol] = f2bf(v);
            }
        }
    }
}

// ======== GEMM2: y = hsb[8192,1024] @ W2t^T + dx(zb 1536+), fused residual into h.
// 256x128 tile, BK=64, 8 waves (2Mx4N, wave = 128x32), 8-phase schedule.
__global__ __launch_bounds__(512, 2)
void gemm2_kernel(const ushort* __restrict__ A, const ushort* __restrict__ Wt,
                  const ushort* __restrict__ zb, float* __restrict__ h)
{
    constexpr int K = 1024, NIT = 8;  // 16 K-tiles of 64
    __shared__ __align__(16) char lds[98304];   // 2 bufs x (A 32K + B 16K)
    const int tid = threadIdx.x, lane = tid & 63, wid = tid >> 6;
    const int wm = wid >> 2, wn = wid & 3;
    int lin = blockIdx.x;
    lin = (lin & 7) * 16 + (lin >> 3);           // 128%8==0
    const int row0 = (lin >> 2) * 256, col0 = (lin & 3) * 128;
    const int rl = lane & 15, gb = lane >> 4;
    const int pg0 = ((gb ^ (rl & 7)) << 4);
    const int pg1 = (((4 + gb) ^ (rl & 7)) << 4);
    const int srow = tid >> 3;
    const int sg   = (tid & 7) ^ (srow & 7);
    const int ldsw = wid * 1024;

    f32x4 acc[8][2] = {};
    bf16x8 aF[8], bF0[2], bF1[2];

#define STG_A2(buf, hh, kt) do { \
    const ushort* gp_ = A + (size_t)(row0 + (hh)*128 + srow)*K + (kt)*64 + sg*8; \
    char* lp_ = lds + (buf)*49152 + (hh)*16384 + ldsw; \
    gload16(gp_, lp_); gload16(gp_ + (size_t)64*K, lp_ + 8192); } while(0)
#define STG_B2(buf, kt) do { \
    const ushort* gp_ = Wt + (size_t)(col0 + srow)*K + (kt)*64 + sg*8; \
    char* lp_ = lds + (buf)*49152 + 32768 + ldsw; \
    gload16(gp_, lp_); gload16(gp_ + (size_t)64*K, lp_ + 8192); } while(0)
#define LDA2(buf, Mh) { _Pragma("unroll") for (int m2 = 0; m2 < 4; ++m2) { \
    const int rb_ = (buf)*49152 + (wm*128 + (Mh)*64 + m2*16 + rl)*128; \
    aF[m2*2+0] = *(const bf16x8*)(lds + rb_ + pg0); \
    aF[m2*2+1] = *(const bf16x8*)(lds + rb_ + pg1); } }
#define LDB2(buf, nn, dst) { \
    const int rb_ = (buf)*49152 + 32768 + (wn*32 + (nn)*16 + rl)*128; \
    dst[0] = *(const bf16x8*)(lds + rb_ + pg0); \
    dst[1] = *(const bf16x8*)(lds + rb_ + pg1); }
#define MM8(Mh, nn, bsrc) { _Pragma("unroll") for (int m2 = 0; m2 < 4; ++m2) { \
      acc[(Mh)*4+m2][nn] = __builtin_amdgcn_mfma_f32_16x16x32_bf16(aF[m2*2+0], bsrc[0], acc[(Mh)*4+m2][nn], 0,0,0); \
      acc[(Mh)*4+m2][nn] = __builtin_amdgcn_mfma_f32_16x16x32_bf16(aF[m2*2+1], bsrc[1], acc[(Mh)*4+m2][nn], 0,0,0); } }

    // prologue: K-tile0 fully + {B, A0} of K-tile1
    STG_B2(0,0); STG_A2(0,0,0); STG_A2(0,1,0);
    STG_B2(1,1); STG_A2(1,0,1);
    asm volatile("s_waitcnt vmcnt(4)" ::: "memory");
    __builtin_amdgcn_s_barrier();

    for (int t = 0; t < NIT; ++t) {
        const bool last = (t == NIT-1);
        // ph1
        LDA2(0,0); LDB2(0,0,bF0);
        STG_A2(1,1,2*t+1);
        PH_SYNC_IN; MM8(0,0,bF0); PH_SYNC_OUT;
        // ph2
        LDB2(0,1,bF1);
        PH_SYNC_IN; MM8(0,1,bF1); PH_SYNC_OUT;
        // ph3
        LDA2(0,1);
        if (!last) STG_B2(0,2*t+2);
        PH_SYNC_IN; MM8(1,0,bF0); PH_SYNC_OUT;
        // ph4
        if (!last) STG_A2(0,0,2*t+2);
        PH_SYNC_IN; MM8(1,1,bF1);
        __builtin_amdgcn_s_setprio(0);
        if (last) { asm volatile("s_waitcnt vmcnt(0)" ::: "memory"); }
        else      { asm volatile("s_waitcnt vmcnt(4)" ::: "memory"); }
        __builtin_amdgcn_s_barrier();
        // ph5
        LDA2(1,0); LDB2(1,0,bF0);
        if (!last) STG_A2(0,1,2*t+2);
        PH_SYNC_IN; MM8(0,0,bF0); PH_SYNC_OUT;
        // ph6
        LDB2(1,1,bF1);
        PH_SYNC_IN; MM8(0,1,bF1); PH_SYNC_OUT;
        // ph7
        LDA2(1,1);
        if (!last) STG_B2(1,2*t+3);
        PH_SYNC_IN; MM8(1,0,bF0); PH_SYNC_OUT;
        // ph8
        if (!last) STG_A2(1,0,2*t+3);
        PH_SYNC_IN; MM8(1,1,bF1);
        __builtin_amdgcn_s_setprio(0);
        if (last) { asm volatile("s_waitcnt vmcnt(0)" ::: "memory"); }
        else      { asm volatile("s_waitcnt vmcnt(4)" ::: "memory"); }
        __builtin_amdgcn_s_barrier();
    }
#undef STG_A2
#undef STG_B2
#undef LDA2
#undef LDB2
#undef MM8

    const int rbase = (lane >> 4)*4;
    #pragma unroll
    for (int m = 0; m < 8; ++m) {
        #pragma unroll
        for (int n = 0; n < 2; ++n) {
            const int gcol = col0 + wn*32 + n*16 + rl;   // parity(gcol)==parity(lane)
            #pragma unroll
            for (int r = 0; r < 4; ++r) {
                const int grow = row0 + wm*128 + m*16 + rbase + r;
                float v = acc[m][n][r] + bf2f(zb[(size_t)grow*2048 + 1536 + gcol]);
                const float p = __shfl_xor(v, 1);
                const float yr = (gcol & 1) ? p : v;
                h[(size_t)grow*512 + gcol] += 0.1f*(yr*v + v);
            }
        }
    }
}

// ---------------- scan pass 1: per-chunk (P, h_end) with h_start=0 (read-only over zb)
__global__ __launch_bounds__(256)
void scan_part1(const ushort* __restrict__ zb, const float* __restrict__ theta,
                const float* __restrict__ dp, float4* __restrict__ PH)
{
    const int c = blockIdx.x, b = blockIdx.y;
    const int s = blockIdx.z*256 + threadIdx.x;
    const float th = theta[s], ct = cosf(th), st = sinf(th);
    const float damp = 0.5f + 0.5f/(1.0f + __expf(-dp[s]));
    float hr = 0.f, hi = 0.f, Pr = 1.f, Pi = 0.f;
    const ushort* row = zb + (size_t)(b*Tn + c*TC)*2048;
    for (int t = 0; t < TC; ++t, row += 2048) {
        const float br = bf2f(row[s]), bi = bf2f(row[512+s]), g = bf2f(row[1024+s]);
        const float mm = (1.0f - g)*damp;
        const float mc = mm*ct, ms = mm*st;
        const float rr = mc*hr - ms*hi, ri = ms*hr + mc*hi;
        hr = g*br + rr;  hi = g*bi + ri;
        const float pr = mc*Pr - ms*Pi, pi = ms*Pr + mc*Pi;
        Pr = pr; Pi = pi;
    }
    PH[((size_t)c*Bn + b)*Sn + s] = make_float4(Pr, Pi, hr, hi);
}

// ---------------- scan pass 2: sequential combine across chunks (tiny)
__global__ __launch_bounds__(256)
void scan_combine(const float4* __restrict__ PH, const float* __restrict__ h0,
                  float2* __restrict__ cin)
{
    const int idx = blockIdx.x*256 + threadIdx.x;   // b*S + s
    const int b = idx / Sn, s = idx % Sn;
    float cr = h0[(size_t)idx*2], ci = h0[(size_t)idx*2 + 1];
    for (int c = 0; c < CHK; ++c) {
        const size_t o = ((size_t)c*Bn + b)*Sn + s;
        cin[o] = make_float2(cr, ci);
        const float4 ph = PH[o];
        const float nr = ph.z + ph.x*cr - ph.y*ci;
        const float ni = ph.w + ph.y*cr + ph.x*ci;
        cr = nr; ci = ni;
    }
}

// ---------------- scan pass 3: exact scan with carry-in, write bf16 [hs_r|hs_i]
__global__ __launch_bounds__(256)
void scan_apply(const ushort* __restrict__ zb, const float* __restrict__ theta,
                const float* __restrict__ dp, const float2* __restrict__ cin,
                ushort* __restrict__ hsb)
{
    const int c = blockIdx.x, b = blockIdx.y;
    const int s = blockIdx.z*256 + threadIdx.x;
    const float th = theta[s], ct = cosf(th), st = sinf(th);
    const float damp = 0.5f + 0.5f/(1.0f + __expf(-dp[s]));
    const float2 c0 = cin[((size_t)c*Bn + b)*Sn + s];
    float hr = c0.x, hi = c0.y;
    const ushort* row = zb + (size_t)(b*Tn + c*TC)*2048;
    ushort* hrow = hsb + (size_t)(b*Tn + c*TC)*1024;
    for (int t = 0; t < TC; ++t, row += 2048, hrow += 1024) {
        const float br = bf2f(row[s]), bi = bf2f(row[512+s]), g = bf2f(row[1024+s]);
        const float mm = (1.0f - g)*damp;
        const float mc = mm*ct, ms = mm*st;
        const float rr = mc*hr - ms*hi, ri = ms*hr + mc*hi;
        hr = g*br + rr;  hi = g*bi + ri;
        hrow[s]       = f2bf(hr);
        hrow[512 + s] = f2bf(hi);
    }
}

// ---------------- weight prep: W1t[2048][512] bf16; dx cols interleaved (yr,yi)
__global__ __launch_bounds__(256)
void prep_w1(const float* __restrict__ Bwr, const float* __restrict__ Bwi,
             const float* __restrict__ Dwr, const float* __restrict__ Dwi,
             const float* __restrict__ Gw, ushort* __restrict__ W1t)
{
    const int l = blockIdx.y;
    const int idx = blockIdx.x*256 + threadIdx.x;   // n*512 + k
    const int n = idx >> 9, k = idx & 511;
    const float* bwr = Bwr + (size_t)l*Dn*Sn;
    const float* bwi = Bwi + (size_t)l*Dn*Sn;
    const float* dwr = Dwr + (size_t)l*Dn*Dn;
    const float* dwi = Dwi + (size_t)l*Dn*Dn;
    const float* gw  = Gw  + (size_t)l*2*Dn*Sn;
    float v;
    if (n < 512)        { const int s = n;      v = (k < 256) ? bwr[k*Sn + s] : -bwi[(k-256)*Sn + s]; }
    else if (n < 1024)  { const int s = n-512;  v = (k < 256) ? bwi[k*Sn + s] :  bwr[(k-256)*Sn + s]; }
    else if (n < 1536)  { const int s = n-1024; v = gw[(size_t)k*Sn + s]; }
    else {
        const int j = n - 1536, d = j >> 1;
        if ((j & 1) == 0) v = (k < 256) ? dwr[k*Dn + d] : -dwi[(k-256)*Dn + d];
        else              v = (k < 256) ? dwi[k*Dn + d] :  dwr[(k-256)*Dn + d];
    }
    W1t[(size_t)l*2048*512 + idx] = f2bf(v);
}

// ---------------- weight prep: W2t[512][1024] bf16, output cols interleaved (yr,yi)
__global__ __launch_bounds__(256)
void prep_w2(const float* __restrict__ Cwr, const float* __restrict__ Cwi,
             ushort* __restrict__ W2t)
{
    const int l = blockIdx.y;
    const int idx = blockIdx.x*256 + threadIdx.x;   // n*1024 + k
    const int n = idx >> 10, k = idx & 1023;
    const float* cwr = Cwr + (size_t)l*Sn*Dn;
    const float* cwi = Cwi + (size_t)l*Sn*Dn;
    const int d = n >> 1;
    float v;
    if ((n & 1) == 0) v = (k < 512) ? cwr[k*Dn + d] : -cwi[(k-512)*Dn + d];
    else              v = (k < 512) ? cwi[k*Dn + d] :  cwr[(k-512)*Dn + d];
    W2t[(size_t)l*512*1024 + idx] = f2bf(v);
}

// ---------------- bias prep
__global__ __launch_bounds__(256)
void prep_bias(const float* __restrict__ gb, float* __restrict__ biasf)
{
    const int l = blockIdx.y;
    const int n = blockIdx.x*256 + threadIdx.x;
    biasf[(size_t)l*2048 + n] = (n >= 1024 && n < 1536) ? gb[(size_t)l*Sn + n - 1024] : 0.0f;
}

extern "C" void kernel_launch(void* const* d_in, const int* in_sizes, int n_in,
                              void* d_out, int out_size, void* d_ws, size_t ws_size,
                              hipStream_t stream)
{
    const float* x      = (const float*)d_in[0];
    const float* h0     = (const float*)d_in[1];
    const float* theta  = (const float*)d_in[2];
    const float* dp     = (const float*)d_in[3];
    const float* B_wr   = (const float*)d_in[4];
    const float* B_wi   = (const float*)d_in[5];
    const float* C_wr   = (const float*)d_in[6];
    const float* C_wi   = (const float*)d_in[7];
    const float* D_wr   = (const float*)d_in[8];
    const float* D_wi   = (const float*)d_in[9];
    const float* gate_w = (const float*)d_in[10];
    const float* gate_b = (const float*)d_in[11];
    const float* norm_g = (const float*)d_in[12];
    const float* out_g  = (const float*)d_in[13];
    float* out = (float*)d_out;

    char* w = (char*)d_ws;
    float*  h     = (float*)w;   w += (size_t)BT*512*4;        // 16 MB
    float*  biasf = (float*)w;   w += (size_t)8*2048*4;        // 64 KB
    float4* PH    = (float4*)w;  w += (size_t)CHK*Bn*Sn*16;    // 1 MB
    float2* cin   = (float2*)w;  w += (size_t)CHK*Bn*Sn*8;     // 0.5 MB
    ushort* zb    = (ushort*)w;  w += (size_t)BT*2048*2;       // 32 MB
    ushort* xn    = (ushort*)w;  w += (size_t)BT*512*2;        // 8 MB
    ushort* hsb   = (ushort*)w;  w += (size_t)BT*1024*2;       // 16 MB
    ushort* W1t   = (ushort*)w;  w += (size_t)Lnum*2048*512*2; // 16 MB
    ushort* W2t   = (ushort*)w;  w += (size_t)Lnum*512*1024*2; // 8 MB

    hipMemcpyAsync(h, x, sizeof(float)*(size_t)BT*Dn*2, hipMemcpyDeviceToDevice, stream);

    prep_w1<<<dim3(2048*512/256, Lnum), 256, 0, stream>>>(B_wr, B_wi, D_wr, D_wi, gate_w, W1t);
    prep_w2<<<dim3(512*1024/256, Lnum), 256, 0, stream>>>(C_wr, C_wi, W2t);
    prep_bias<<<dim3(8, Lnum), 256, 0, stream>>>(gate_b, biasf);

    const dim3 gs(CHK, Bn, Sn/256);

    for (int l = 0; l < Lnum; ++l) {
        norm_kernel<<<BT, 256, 0, stream>>>(h, norm_g + (size_t)l*Dn, xn);

        gemm1_kernel<<<256, 512, 0, stream>>>(xn, W1t + (size_t)l*2048*512, zb,
                                              biasf + (size_t)l*2048);

        scan_part1<<<gs, 256, 0, stream>>>(zb, theta + (size_t)l*Sn, dp + (size_t)l*Sn, PH);
        scan_combine<<<(Bn*Sn)/256, 256, 0, stream>>>(PH, h0 + (size_t)l*Bn*Sn*2, cin);
        scan_apply<<<gs, 256, 0, stream>>>(zb, theta + (size_t)l*Sn, dp + (size_t)l*Sn, cin, hsb);

        gemm2_kernel<<<128, 512, 0, stream>>>(hsb, W2t + (size_t)l*512*1024, zb, h);
    }

    out_norm_kernel<<<BT, 256, 0, stream>>>(h, out_g, out);
}